// Round 14
// baseline (7244.626 us; speedup 1.0000x reference)
//
#include <hip/hip_runtime.h>
#include <math.h>

#define NL 200
#define SLICE 131072ul  // 512 k * 256 b floats

// ---- workspace layout (float offsets), activations stored [k][b] ----
// BIG[201][512][256]: slice u+1 = sessionT[u]; GRU writes h_t = sseqT[t] slice t.
// AUGRU reuses dead slices: h_aug[0] -> slice 200, h_aug[t>=1] -> slice t.
#define BIG_OFF   0ul
#define LG_OFF    26345472ul   // logits [200][256]
#define ATT_OFF   26396672ul   // att    [200][256]
#define VT_OFF    26447872ul   // vtT    [512][256]
#define HR_OFF    26841088ul   // r*h [512][256] (sc1 both ways; address-reused)
#define FLAGS_OFF 26972160ul   // u32 flags: gf[2][128] @0, af1[4][64] @256, af2[4][64] @512

typedef __attribute__((ext_vector_type(2))) __fp16 h2;  // matches fdot2 builtin type

__device__ __forceinline__ float sigmoidf_(float x) { return 1.0f / (1.0f + expf(-x)); }

// pack two f32 -> half2, RNE
__device__ __forceinline__ unsigned pk2(float a, float b) {
  union { h2 h; unsigned u; } x;
  x.h.x = (__fp16)a; x.h.y = (__fp16)b;
  return x.u;
}
__device__ __forceinline__ h2 pkh(float a, float b) {
  h2 r; r.x = (__fp16)a; r.y = (__fp16)b; return r;
}
__device__ __forceinline__ float fd2(unsigned w, h2 a, float c) {
  union { unsigned u; h2 h; } x; x.u = w;
  return __builtin_amdgcn_fdot2(a, x.h, c, false);
}

// ---- LLC-direct (sc1) accessors: relaxed agent atomics, no fences ----
__device__ __forceinline__ float cohld1(const float* p) {
  return __hip_atomic_load(p, __ATOMIC_RELAXED, __HIP_MEMORY_SCOPE_AGENT);
}
__device__ __forceinline__ float2 cohld2(const float* p) {
  union { double d; float2 f; } u;
  u.d = __hip_atomic_load((const double*)p, __ATOMIC_RELAXED, __HIP_MEMORY_SCOPE_AGENT);
  return u.f;
}
__device__ __forceinline__ void cohst1(float* p, float v) {
  __hip_atomic_store(p, v, __ATOMIC_RELAXED, __HIP_MEMORY_SCOPE_AGENT);
}

// ---- grid waits ----
__device__ __forceinline__ void gwait64(const unsigned* f, unsigned val) {
  const int i = threadIdx.x & 63;
  int guard = 0;
  while (__hip_atomic_load(f + i, __ATOMIC_RELAXED, __HIP_MEMORY_SCOPE_AGENT) < val) {
    if (++guard > (1 << 22)) break;
  }
}
__device__ __forceinline__ void gwait128(const unsigned* f, unsigned val) {
  const int i = threadIdx.x & 63;
  bool d0 = false, d1 = false;
  int guard = 0;
  while (!(d0 && d1)) {
    if (!d0) d0 = __hip_atomic_load(f + i, __ATOMIC_RELAXED, __HIP_MEMORY_SCOPE_AGENT) >= val;
    if (!d1) d1 = __hip_atomic_load(f + i + 64, __ATOMIC_RELAXED, __HIP_MEMORY_SCOPE_AGENT) >= val;
    if (++guard > (1 << 22)) break;
  }
}

__global__ void init_kernel(float* __restrict__ ws) {
  unsigned* const fl = (unsigned*)(ws + FLAGS_OFF);
  for (int j = threadIdx.x; j < 768; j += 256) fl[j] = 0u;
}

// ---- transpose session -> BIG slices 1..200 as [k][b] (sc1 stores) ----
__global__ __launch_bounds__(256) void transpose_kernel(const float* __restrict__ in,
                                                        float* __restrict__ ws) {
  __shared__ float tile[64][65];
  const int tx = threadIdx.x & 63, ty = threadIdx.x >> 6;
  const size_t tk0 = (size_t)blockIdx.x * 64;
  const int b0 = blockIdx.y * 64;
#pragma unroll
  for (int r = 0; r < 16; ++r) {
    const int bb = ty + 4 * r;
    tile[bb][tx] = in[(size_t)(b0 + bb) * 102400 + tk0 + tx];
  }
  __syncthreads();
  float* const big1 = ws + BIG_OFF + SLICE;
#pragma unroll
  for (int r = 0; r < 16; ++r) {
    const int kk = ty + 4 * r;
    cohst1(big1 + (tk0 + kk) * 256 + b0 + tx, tile[tx][kk]);
  }
}

// ---- vtT[d][b] = sum_e w[d,e] * target[b,e] (fp32) ----
__global__ __launch_bounds__(256) void vt_kernel(const float* __restrict__ w,
                                                 const float* __restrict__ tgt,
                                                 float* __restrict__ ws) {
  __shared__ float t_s[512];
  const int b = blockIdx.x, tid = threadIdx.x;
  for (int i = tid; i < 512; i += 256) t_s[i] = tgt[(size_t)b * 512 + i];
  __syncthreads();
  const int wv = tid >> 6, lane = tid & 63;
  for (int d = wv; d < 512; d += 4) {
    const float* const wr = w + (size_t)d * 512;
    const float4 a  = *(const float4*)(wr + lane * 8);
    const float4 a2 = *(const float4*)(wr + lane * 8 + 4);
    float s = a.x * t_s[lane * 8 + 0] + a.y * t_s[lane * 8 + 1] +
              a.z * t_s[lane * 8 + 2] + a.w * t_s[lane * 8 + 3] +
              a2.x * t_s[lane * 8 + 4] + a2.y * t_s[lane * 8 + 5] +
              a2.z * t_s[lane * 8 + 6] + a2.w * t_s[lane * 8 + 7];
    for (int off = 32; off > 0; off >>= 1) s += __shfl_xor(s, off);
    if (lane == 0) ws[VT_OFF + (size_t)d * 256 + b] = s;
  }
}

// ---- persistent GRU: fp32 (unchanged; passed at 1.95e-3) ----
__global__ __launch_bounds__(512) void gru_kernel(const float* __restrict__ wih,
                                                  const float* __restrict__ whh,
                                                  const float* __restrict__ bih,
                                                  const float* __restrict__ bhh,
                                                  float* __restrict__ ws) {
  __shared__ float wxT[512 * 16];
  __shared__ float whT[512 * 16];
  __shared__ float red[16 * 8 * 130];
  __shared__ float bihs[12], bhhs[12];

  const int bg = blockIdx.x >> 7;
  const int ng = blockIdx.x & 127;
  const int b0 = bg << 7, c0 = ng << 2;
  const int tid = threadIdx.x;

  for (int i = tid; i < 512 * 16; i += 512) {
    const int k = i >> 4, s = i & 15;
    if (s < 12) {
      const int grow = ((s >> 2) << 9) + c0 + (s & 3);
      wxT[i] = wih[(size_t)grow * 512 + k];
      whT[i] = whh[(size_t)grow * 512 + k];
    }
  }
  if (tid < 12) {
    const int grow = ((tid >> 2) << 9) + c0 + (tid & 3);
    bihs[tid] = bih[grow];
    bhhs[tid] = bhh[grow];
  }
  __syncthreads();

  float* const big = ws + BIG_OFF;
  unsigned* const gf = (unsigned*)(ws + FLAGS_OFF) + (bg << 7);

  const int wv = tid >> 6, l = tid & 63;
  const int k0 = wv << 6;
  const int boff = b0 + 2 * l;
  const int qg = tid >> 7;
  const int rr = tid & 127;
  const size_t og = (size_t)(c0 + qg) * 256 + b0 + rr;

  float2 ax[12];
#pragma unroll
  for (int s = 0; s < 12; ++s) ax[s] = make_float2(0.0f, 0.0f);
  {
    const float* const xp = big + 1ul * SLICE + boff;
    for (int bq = 0; bq < 4; ++bq) {
      const int kb = k0 + bq * 16;
      float2 v[16];
#pragma unroll
      for (int j = 0; j < 16; ++j) v[j] = cohld2(xp + (size_t)(kb + j) * 256);
#pragma unroll
      for (int j = 0; j < 16; ++j) {
        const float4* const wr = (const float4*)(wxT + (size_t)(kb + j) * 16);
        float w12[12];
        *(float4*)&w12[0] = wr[0];
        *(float4*)&w12[4] = wr[1];
        *(float4*)&w12[8] = wr[2];
#pragma unroll
        for (int s = 0; s < 12; ++s) {
          ax[s].x += v[j].x * w12[s];
          ax[s].y += v[j].y * w12[s];
        }
      }
    }
  }

  for (int t = 0; t < NL; ++t) {
    if (t > 0) {
      if (wv == 0) gwait128(gf, (unsigned)t);
      __syncthreads();
    }
    float2 ah[12];
#pragma unroll
    for (int s = 0; s < 12; ++s) ah[s] = make_float2(0.0f, 0.0f);
    float hprev = 0.0f;
    if (t > 0) {
      const float* const hp = big + (size_t)(t - 1) * SLICE + boff;
      hprev = big[(size_t)(t - 1) * SLICE + og];
      for (int bq = 0; bq < 4; ++bq) {
        const int kb = k0 + bq * 16;
        float2 v[16];
#pragma unroll
        for (int j = 0; j < 16; ++j) v[j] = *(const float2*)(hp + (size_t)(kb + j) * 256);
#pragma unroll
        for (int j = 0; j < 16; ++j) {
          const float4* const wr = (const float4*)(whT + (size_t)(kb + j) * 16);
          float w12[12];
          *(float4*)&w12[0] = wr[0];
          *(float4*)&w12[4] = wr[1];
          *(float4*)&w12[8] = wr[2];
#pragma unroll
          for (int s = 0; s < 12; ++s) {
            ah[s].x += v[j].x * w12[s];
            ah[s].y += v[j].y * w12[s];
          }
        }
      }
    }
#pragma unroll
    for (int s = 0; s < 4; ++s) {
      *(float2*)&red[((size_t)(0 + s) * 8 + wv) * 130 + 2 * l] =
          make_float2(ax[s].x + ah[s].x, ax[s].y + ah[s].y);
      *(float2*)&red[((size_t)(4 + s) * 8 + wv) * 130 + 2 * l] =
          make_float2(ax[4 + s].x + ah[4 + s].x, ax[4 + s].y + ah[4 + s].y);
      *(float2*)&red[((size_t)(8 + s) * 8 + wv) * 130 + 2 * l] = ax[8 + s];
      *(float2*)&red[((size_t)(12 + s) * 8 + wv) * 130 + 2 * l] = ah[8 + s];
    }
    __syncthreads();
    float rp = 0, zp = 0, xnp = 0, hnp = 0;
#pragma unroll
    for (int w8 = 0; w8 < 8; ++w8) {
      rp  += red[((size_t)(0 + qg) * 8 + w8) * 130 + rr];
      zp  += red[((size_t)(4 + qg) * 8 + w8) * 130 + rr];
      xnp += red[((size_t)(8 + qg) * 8 + w8) * 130 + rr];
      hnp += red[((size_t)(12 + qg) * 8 + w8) * 130 + rr];
    }
    const float r = sigmoidf_(rp + bihs[0 + qg] + bhhs[0 + qg]);
    const float z = sigmoidf_(zp + bihs[4 + qg] + bhhs[4 + qg]);
    const float n = tanhf(xnp + bihs[8 + qg] + r * (hnp + bhhs[8 + qg]));
    const float hnew = (1.0f - z) * n + z * hprev;
    cohst1(big + (size_t)t * SLICE + og, hnew);
    asm volatile("s_waitcnt vmcnt(0)" ::: "memory");
    __syncthreads();
    if (tid == 0)
      __hip_atomic_store(gf + ng, (unsigned)(t + 1), __ATOMIC_RELAXED, __HIP_MEMORY_SCOPE_AGENT);
    if (t + 1 < NL) {
      const float* const xp = big + (size_t)(t + 2) * SLICE + boff;
#pragma unroll
      for (int s = 0; s < 12; ++s) ax[s] = make_float2(0.0f, 0.0f);
      for (int bq = 0; bq < 4; ++bq) {
        const int kb = k0 + bq * 16;
        float2 v[16];
#pragma unroll
        for (int j = 0; j < 16; ++j) v[j] = cohld2(xp + (size_t)(kb + j) * 256);
#pragma unroll
        for (int j = 0; j < 16; ++j) {
          const float4* const wr = (const float4*)(wxT + (size_t)(kb + j) * 16);
          float w12[12];
          *(float4*)&w12[0] = wr[0];
          *(float4*)&w12[4] = wr[1];
          *(float4*)&w12[8] = wr[2];
#pragma unroll
          for (int s = 0; s < 12; ++s) {
            ax[s].x += v[j].x * w12[s];
            ax[s].y += v[j].y * w12[s];
          }
        }
      }
    }
    asm volatile("" ::: "memory");
  }
}

// ---- attn1 / attn2 (fp32, prior dispatches -> boundary invalidate ok) ----
__global__ __launch_bounds__(256) void attn1_kernel(float* __restrict__ ws) {
  const int l = blockIdx.x, tid = threadIdx.x;
  const float* const sl = ws + BIG_OFF + (size_t)l * SLICE + tid;
  const float* const vtt = ws + VT_OFF + tid;
  float acc = 0.0f;
#pragma unroll 8
  for (int k = 0; k < 512; ++k)
    acc += sl[(size_t)k * 256] * vtt[(size_t)k * 256];
  ws[LG_OFF + (size_t)l * 256 + tid] = acc;
}

__global__ __launch_bounds__(256) void attn2_kernel(float* __restrict__ ws) {
  __shared__ float red[8];
  const int b = blockIdx.x, tid = threadIdx.x;
  const float v = (tid < NL) ? ws[LG_OFF + (size_t)tid * 256 + b] : -3.0e38f;
  float m = v;
  for (int off = 32; off > 0; off >>= 1) m = fmaxf(m, __shfl_xor(m, off));
  if ((tid & 63) == 0) red[tid >> 6] = m;
  __syncthreads();
  m = fmaxf(fmaxf(red[0], red[1]), fmaxf(red[2], red[3]));
  const float e = (tid < NL) ? expf(v - m) : 0.0f;
  float s = e;
  for (int off = 32; off > 0; off >>= 1) s += __shfl_xor(s, off);
  __syncthreads();
  if ((tid & 63) == 0) red[4 + (tid >> 6)] = s;
  __syncthreads();
  s = red[4] + red[5] + red[6] + red[7];
  if (tid < NL) ws[ATT_OFF + (size_t)tid * 256 + b] = e / s;
}

// AUGRU dot (fp16). Activations at k-pair kp0+.. in [0,256); weight row
// offset WOFF (256 for x-part, 0 for h-part). DEPTH = loads in flight.
template <bool COH, int NQ, int SOFF, int WOFF, int DEPTH>
__device__ __forceinline__ void adot(const float* ap, const unsigned* wT24,
                                     int kp0, float* acc) {
  for (int g = 0; g < 32 / DEPTH; ++g) {
    const int kb = kp0 + g * DEPTH;
    float va[DEPTH], vb[DEPTH];
#pragma unroll
    for (int j = 0; j < DEPTH; ++j) {
      const float* p0 = ap + (size_t)(2 * (kb + j)) * 256;
      if (COH) { va[j] = cohld1(p0); vb[j] = cohld1(p0 + 256); }
      else     { va[j] = p0[0]; vb[j] = p0[256]; }
    }
#pragma unroll
    for (int j = 0; j < DEPTH; ++j) {
      const h2 r = pkh(va[j], vb[j]);
      const uint4* wq = (const uint4*)(wT24 + (size_t)(WOFF + kb + j) * 24) + SOFF;
#pragma unroll
      for (int q = 0; q < NQ; ++q) {
        const uint4 qq = wq[q];
        acc[4 * q + 0] = fd2(qq.x, r, acc[4 * q + 0]);
        acc[4 * q + 1] = fd2(qq.y, r, acc[4 * q + 1]);
        acc[4 * q + 2] = fd2(qq.z, r, acc[4 * q + 2]);
        acc[4 * q + 3] = fd2(qq.w, r, acc[4 * q + 3]);
      }
    }
  }
}

// ---- persistent AUGRU: fp16 dots; h_aug in dead BIG slices (L2 h-dot).
// Within this kernel sseq slices are ONLY sc1-read (xdot) before being
// overwritten by h_aug -> no XCD L2 copy can go stale. hr stays sc1. ----
__global__ __launch_bounds__(512) void augru_kernel(const float* __restrict__ rw,
                                                    const float* __restrict__ rbias,
                                                    const float* __restrict__ uw,
                                                    const float* __restrict__ ubias,
                                                    const float* __restrict__ hw,
                                                    const float* __restrict__ hbias,
                                                    float* __restrict__ ws,
                                                    float* __restrict__ out) {
  __shared__ unsigned wT[512 * 24];   // [kp][24] half2-pairs: slot m*8+c
  __shared__ float red[24 * 8 * 66];
  __shared__ float rbs[8], ubs[8], hbs[8];

  const int rg = blockIdx.x >> 6;
  const int cg = blockIdx.x & 63;
  const int r0 = rg << 6, c0 = cg << 3;
  const int tid = threadIdx.x;

  for (int i = tid; i < 512 * 24; i += 512) {
    const int kp = i / 24, s = i % 24;
    const int m = s >> 3, c = s & 7;
    const float* const wm = (m == 0) ? rw : (m == 1) ? uw : hw;
    wT[i] = pk2(wm[(size_t)(c0 + c) * 1024 + 2 * kp],
                wm[(size_t)(c0 + c) * 1024 + 2 * kp + 1]);
  }
  if (tid < 8) {
    rbs[tid] = rbias[c0 + tid];
    ubs[tid] = ubias[c0 + tid];
    hbs[tid] = hbias[c0 + tid];
  }
  __syncthreads();

  float* const big = ws + BIG_OFF;
  float* const hrg = ws + HR_OFF;
  const float* const att = ws + ATT_OFF;
  unsigned* const fbase = (unsigned*)(ws + FLAGS_OFF);
  unsigned* const af1 = fbase + 256 + (rg << 6);
  unsigned* const af2 = fbase + 512 + (rg << 6);

  const int wv = tid >> 6, l = tid & 63;
  const int kp0 = wv << 5;
  const int boff = r0 + l;
  const int cq = tid >> 6;
  const int rr = tid & 63;
  const size_t og = (size_t)(c0 + cq) * 256 + r0 + rr;

  // prologue: x-dot t=0 (sseqT[0]; sc1 loads keep big slices L2-virgin)
  float ax[24];
#pragma unroll
  for (int s = 0; s < 24; ++s) ax[s] = 0.0f;
  adot<true, 6, 0, 256, 8>(big + boff, wT, kp0, ax);

  for (int t = 0; t < NL; ++t) {
    if (t > 0) {
      if (wv == 0) gwait64(af2, (unsigned)t);
      __syncthreads();
    }
    // h source: t=0 -> GRU final (slice 199); t=1 -> h_aug[0] (slice 200);
    // else h_aug[t-1] (slice t-1). All fresh-address -> normal L2 loads.
    const float* const hsrc =
        big + ((t == 0) ? 199ul : (t == 1) ? 200ul : (size_t)(t - 1)) * SLICE;
    const float hcur = hsrc[og];
    float ah[16];
#pragma unroll
    for (int s = 0; s < 16; ++s) ah[s] = 0.0f;
    adot<false, 4, 0, 0, 8>(hsrc + boff, wT, kp0, ah);
#pragma unroll
    for (int c = 0; c < 8; ++c) {
      red[((size_t)(0 + c) * 8 + wv) * 66 + l] = ax[c] + ah[c];
      red[((size_t)(8 + c) * 8 + wv) * 66 + l] = ax[8 + c] + ah[8 + c];
      red[((size_t)(16 + c) * 8 + wv) * 66 + l] = ax[16 + c];
    }
    __syncthreads();
    float rp = 0, up = 0, xhp = 0;
#pragma unroll
    for (int w8 = 0; w8 < 8; ++w8) {
      rp  += red[((size_t)(0 + cq) * 8 + w8) * 66 + rr];
      up  += red[((size_t)(8 + cq) * 8 + w8) * 66 + rr];
      xhp += red[((size_t)(16 + cq) * 8 + w8) * 66 + rr];
    }
    const float rgate = sigmoidf_(rp + rbs[cq]);
    const float ug = sigmoidf_(up + ubs[cq]);
    cohst1(hrg + og, rgate * hcur);
    asm volatile("s_waitcnt vmcnt(0)" ::: "memory");
    __syncthreads();
    if (tid == 0)
      __hip_atomic_store(af1 + cg, (unsigned)(t + 1), __ATOMIC_RELAXED, __HIP_MEMORY_SCOPE_AGENT);
    // pipelined x-dot for t+1 inside the af1 window (sc1 loads)
    if (t + 1 < NL) {
#pragma unroll
      for (int s = 0; s < 24; ++s) ax[s] = 0.0f;
      adot<true, 6, 0, 256, 8>(big + (size_t)(t + 1) * SLICE + boff, wT, kp0, ax);
    }
    asm volatile("" ::: "memory");
    if (wv == 0) gwait64(af1, (unsigned)(t + 1));
    __syncthreads();
    // phase2: hhat (hr via sc1, 16-deep batches to halve latency exposure)
    float ahh[8];
#pragma unroll
    for (int s = 0; s < 8; ++s) ahh[s] = 0.0f;
    adot<true, 2, 4, 0, 16>(hrg + boff, wT, kp0, ahh);
#pragma unroll
    for (int c = 0; c < 8; ++c)
      red[((size_t)c * 8 + wv) * 66 + l] = ahh[c];
    __syncthreads();
    float hhp = 0;
#pragma unroll
    for (int w8 = 0; w8 < 8; ++w8)
      hhp += red[((size_t)cq * 8 + w8) * 66 + rr];
    const float hh = tanhf(hhp + xhp + hbs[cq]);
    const float av = att[(size_t)t * 256 + r0 + rr];
    const float u = av * ug;
    const float hn = (1.0f - u) * hcur + u * hh;
    if (t == NL - 1) {
      out[(size_t)(r0 + rr) * 512 + c0 + cq] = hn;
    } else {
      // h_aug[t] -> dead slice (t=0 -> 200, else t); all blocks consumed
      // sseq[t] (xdot) before passing af2(t), so the overwrite is safe.
      float* const hdst = big + ((t == 0) ? 200ul : (size_t)t) * SLICE;
      cohst1(hdst + og, hn);
    }
    asm volatile("s_waitcnt vmcnt(0)" ::: "memory");
    __syncthreads();
    if (tid == 0)
      __hip_atomic_store(af2 + cg, (unsigned)(t + 1), __ATOMIC_RELAXED, __HIP_MEMORY_SCOPE_AGENT);
  }
}

extern "C" void kernel_launch(void* const* d_in, const int* in_sizes, int n_in,
                              void* d_out, int out_size, void* d_ws, size_t ws_size,
                              hipStream_t stream) {
  (void)in_sizes; (void)n_in; (void)out_size; (void)ws_size;
  const float* session = (const float*)d_in[0];
  const float* target  = (const float*)d_in[1];
  const float* w       = (const float*)d_in[2];
  const float* wih     = (const float*)d_in[3];
  const float* whh     = (const float*)d_in[4];
  const float* bih     = (const float*)d_in[5];
  const float* bhh     = (const float*)d_in[6];
  const float* rw      = (const float*)d_in[7];
  const float* rb      = (const float*)d_in[8];
  const float* uw      = (const float*)d_in[9];
  const float* ub      = (const float*)d_in[10];
  const float* hw      = (const float*)d_in[11];
  const float* hb      = (const float*)d_in[12];
  float* ws  = (float*)d_ws;
  float* out = (float*)d_out;

  hipLaunchKernelGGL(init_kernel, dim3(1), dim3(256), 0, stream, ws);
  hipLaunchKernelGGL(transpose_kernel, dim3(1600, 4), dim3(256), 0, stream, session, ws);
  hipLaunchKernelGGL(vt_kernel, dim3(256), dim3(256), 0, stream, w, target, ws);
  hipLaunchKernelGGL(gru_kernel, dim3(256), dim3(512), 0, stream,
                     wih, whh, bih, bhh, ws);
  hipLaunchKernelGGL(attn1_kernel, dim3(200), dim3(256), 0, stream, ws);
  hipLaunchKernelGGL(attn2_kernel, dim3(256), dim3(256), 0, stream, ws);
  hipLaunchKernelGGL(augru_kernel, dim3(256), dim3(512), 0, stream,
                     rw, rb, uw, ub, hw, hb, ws, out);
}

// Round 15
// 6959.055 us; speedup vs baseline: 1.0410x; 1.0410x over previous
//
#include <hip/hip_runtime.h>
#include <math.h>

#define NL 200
#define SLICE 131072ul  // 512 k * 256 b floats

// ---- workspace layout (float offsets), activations stored [k][b] ----
// BIG[201][512][256]: slice u+1 = sessionT[u]; GRU writes h_t = sseqT[t] slice t.
// AUGRU reuses dead slices: h_aug[0] -> slice 200, h_aug[t>=1] -> slice t.
#define BIG_OFF   0ul
#define LG_OFF    26345472ul   // logits [200][256]
#define ATT_OFF   26396672ul   // att    [200][256]
#define VT_OFF    26447872ul   // vtT    [512][256]
#define HR_OFF    26841088ul   // r*h [512][256] (sc1 both ways; address-reused)
#define FLAGS_OFF 26972160ul   // u32 flags, ONE PER 64B LINE (stride 16):
                               // gf[2][128] @slot 0, af1[4][64] @256, af2[4][64] @512
#define FSTRIDE   16           // u32 per flag slot (64B line)

typedef __attribute__((ext_vector_type(2))) __fp16 h2;  // matches fdot2 builtin type

__device__ __forceinline__ float sigmoidf_(float x) { return 1.0f / (1.0f + expf(-x)); }

// pack two f32 -> half2, RNE
__device__ __forceinline__ unsigned pk2(float a, float b) {
  union { h2 h; unsigned u; } x;
  x.h.x = (__fp16)a; x.h.y = (__fp16)b;
  return x.u;
}
__device__ __forceinline__ h2 pkh(float a, float b) {
  h2 r; r.x = (__fp16)a; r.y = (__fp16)b; return r;
}
__device__ __forceinline__ float fd2(unsigned w, h2 a, float c) {
  union { unsigned u; h2 h; } x; x.u = w;
  return __builtin_amdgcn_fdot2(a, x.h, c, false);
}

// ---- LLC-direct (sc1) accessors: relaxed agent atomics, no fences ----
__device__ __forceinline__ float cohld1(const float* p) {
  return __hip_atomic_load(p, __ATOMIC_RELAXED, __HIP_MEMORY_SCOPE_AGENT);
}
__device__ __forceinline__ float2 cohld2(const float* p) {
  union { double d; float2 f; } u;
  u.d = __hip_atomic_load((const double*)p, __ATOMIC_RELAXED, __HIP_MEMORY_SCOPE_AGENT);
  return u.f;
}
__device__ __forceinline__ void cohst1(float* p, float v) {
  __hip_atomic_store(p, v, __ATOMIC_RELAXED, __HIP_MEMORY_SCOPE_AGENT);
}

// ---- grid waits: padded flag lines (1 writer/line), s_sleep poll backoff ----
__device__ __forceinline__ void gwait64(const unsigned* f, unsigned val) {
  const int i = threadIdx.x & 63;
  const unsigned* const p = f + (size_t)i * FSTRIDE;
  int guard = 0;
  // fast path: first check without sleeping
  if (__hip_atomic_load(p, __ATOMIC_RELAXED, __HIP_MEMORY_SCOPE_AGENT) >= val) return;
  for (;;) {
    __builtin_amdgcn_s_sleep(1);
    if (__hip_atomic_load(p, __ATOMIC_RELAXED, __HIP_MEMORY_SCOPE_AGENT) >= val) break;
    if (++guard > (1 << 22)) break;  // deadlock escape
  }
}
__device__ __forceinline__ void gwait128(const unsigned* f, unsigned val) {
  const int i = threadIdx.x & 63;
  const unsigned* const p0 = f + (size_t)i * FSTRIDE;
  const unsigned* const p1 = f + (size_t)(i + 64) * FSTRIDE;
  bool d0 = __hip_atomic_load(p0, __ATOMIC_RELAXED, __HIP_MEMORY_SCOPE_AGENT) >= val;
  bool d1 = __hip_atomic_load(p1, __ATOMIC_RELAXED, __HIP_MEMORY_SCOPE_AGENT) >= val;
  int guard = 0;
  while (!(d0 && d1)) {
    __builtin_amdgcn_s_sleep(1);
    if (!d0) d0 = __hip_atomic_load(p0, __ATOMIC_RELAXED, __HIP_MEMORY_SCOPE_AGENT) >= val;
    if (!d1) d1 = __hip_atomic_load(p1, __ATOMIC_RELAXED, __HIP_MEMORY_SCOPE_AGENT) >= val;
    if (++guard > (1 << 22)) break;
  }
}
__device__ __forceinline__ void fpost(unsigned* f, int slot, unsigned val) {
  __hip_atomic_store(f + (size_t)slot * FSTRIDE, val, __ATOMIC_RELAXED, __HIP_MEMORY_SCOPE_AGENT);
}

__global__ void init_kernel(float* __restrict__ ws) {
  unsigned* const fl = (unsigned*)(ws + FLAGS_OFF);
  const int i = blockIdx.x * 256 + threadIdx.x;
  for (int j = i; j < 768 * FSTRIDE; j += 4 * 256) fl[j] = 0u;
}

// ---- transpose session -> BIG slices 1..200 as [k][b] (sc1 stores) ----
__global__ __launch_bounds__(256) void transpose_kernel(const float* __restrict__ in,
                                                        float* __restrict__ ws) {
  __shared__ float tile[64][65];
  const int tx = threadIdx.x & 63, ty = threadIdx.x >> 6;
  const size_t tk0 = (size_t)blockIdx.x * 64;
  const int b0 = blockIdx.y * 64;
#pragma unroll
  for (int r = 0; r < 16; ++r) {
    const int bb = ty + 4 * r;
    tile[bb][tx] = in[(size_t)(b0 + bb) * 102400 + tk0 + tx];
  }
  __syncthreads();
  float* const big1 = ws + BIG_OFF + SLICE;
#pragma unroll
  for (int r = 0; r < 16; ++r) {
    const int kk = ty + 4 * r;
    cohst1(big1 + (tk0 + kk) * 256 + b0 + tx, tile[tx][kk]);
  }
}

// ---- vtT[d][b] = sum_e w[d,e] * target[b,e] (fp32) ----
__global__ __launch_bounds__(256) void vt_kernel(const float* __restrict__ w,
                                                 const float* __restrict__ tgt,
                                                 float* __restrict__ ws) {
  __shared__ float t_s[512];
  const int b = blockIdx.x, tid = threadIdx.x;
  for (int i = tid; i < 512; i += 256) t_s[i] = tgt[(size_t)b * 512 + i];
  __syncthreads();
  const int wv = tid >> 6, lane = tid & 63;
  for (int d = wv; d < 512; d += 4) {
    const float* const wr = w + (size_t)d * 512;
    const float4 a  = *(const float4*)(wr + lane * 8);
    const float4 a2 = *(const float4*)(wr + lane * 8 + 4);
    float s = a.x * t_s[lane * 8 + 0] + a.y * t_s[lane * 8 + 1] +
              a.z * t_s[lane * 8 + 2] + a.w * t_s[lane * 8 + 3] +
              a2.x * t_s[lane * 8 + 4] + a2.y * t_s[lane * 8 + 5] +
              a2.z * t_s[lane * 8 + 6] + a2.w * t_s[lane * 8 + 7];
    for (int off = 32; off > 0; off >>= 1) s += __shfl_xor(s, off);
    if (lane == 0) ws[VT_OFF + (size_t)d * 256 + b] = s;
  }
}

// ---- persistent GRU: fp32 (data path unchanged; passed at 1.95e-3) ----
__global__ __launch_bounds__(512) void gru_kernel(const float* __restrict__ wih,
                                                  const float* __restrict__ whh,
                                                  const float* __restrict__ bih,
                                                  const float* __restrict__ bhh,
                                                  float* __restrict__ ws) {
  __shared__ float wxT[512 * 16];
  __shared__ float whT[512 * 16];
  __shared__ float red[16 * 8 * 130];
  __shared__ float bihs[12], bhhs[12];

  const int bg = blockIdx.x >> 7;
  const int ng = blockIdx.x & 127;
  const int b0 = bg << 7, c0 = ng << 2;
  const int tid = threadIdx.x;

  for (int i = tid; i < 512 * 16; i += 512) {
    const int k = i >> 4, s = i & 15;
    if (s < 12) {
      const int grow = ((s >> 2) << 9) + c0 + (s & 3);
      wxT[i] = wih[(size_t)grow * 512 + k];
      whT[i] = whh[(size_t)grow * 512 + k];
    }
  }
  if (tid < 12) {
    const int grow = ((tid >> 2) << 9) + c0 + (tid & 3);
    bihs[tid] = bih[grow];
    bhhs[tid] = bhh[grow];
  }
  __syncthreads();

  float* const big = ws + BIG_OFF;
  unsigned* const gf = (unsigned*)(ws + FLAGS_OFF) + (size_t)(bg << 7) * FSTRIDE;

  const int wv = tid >> 6, l = tid & 63;
  const int k0 = wv << 6;
  const int boff = b0 + 2 * l;
  const int qg = tid >> 7;
  const int rr = tid & 127;
  const size_t og = (size_t)(c0 + qg) * 256 + b0 + rr;

  float2 ax[12];
#pragma unroll
  for (int s = 0; s < 12; ++s) ax[s] = make_float2(0.0f, 0.0f);
  {
    const float* const xp = big + 1ul * SLICE + boff;
    for (int bq = 0; bq < 4; ++bq) {
      const int kb = k0 + bq * 16;
      float2 v[16];
#pragma unroll
      for (int j = 0; j < 16; ++j) v[j] = cohld2(xp + (size_t)(kb + j) * 256);
#pragma unroll
      for (int j = 0; j < 16; ++j) {
        const float4* const wr = (const float4*)(wxT + (size_t)(kb + j) * 16);
        float w12[12];
        *(float4*)&w12[0] = wr[0];
        *(float4*)&w12[4] = wr[1];
        *(float4*)&w12[8] = wr[2];
#pragma unroll
        for (int s = 0; s < 12; ++s) {
          ax[s].x += v[j].x * w12[s];
          ax[s].y += v[j].y * w12[s];
        }
      }
    }
  }

  for (int t = 0; t < NL; ++t) {
    if (t > 0) {
      if (wv == 0) gwait128(gf, (unsigned)t);
      __syncthreads();
    }
    float2 ah[12];
#pragma unroll
    for (int s = 0; s < 12; ++s) ah[s] = make_float2(0.0f, 0.0f);
    float hprev = 0.0f;
    if (t > 0) {
      const float* const hp = big + (size_t)(t - 1) * SLICE + boff;
      hprev = big[(size_t)(t - 1) * SLICE + og];
      for (int bq = 0; bq < 4; ++bq) {
        const int kb = k0 + bq * 16;
        float2 v[16];
#pragma unroll
        for (int j = 0; j < 16; ++j) v[j] = *(const float2*)(hp + (size_t)(kb + j) * 256);
#pragma unroll
        for (int j = 0; j < 16; ++j) {
          const float4* const wr = (const float4*)(whT + (size_t)(kb + j) * 16);
          float w12[12];
          *(float4*)&w12[0] = wr[0];
          *(float4*)&w12[4] = wr[1];
          *(float4*)&w12[8] = wr[2];
#pragma unroll
          for (int s = 0; s < 12; ++s) {
            ah[s].x += v[j].x * w12[s];
            ah[s].y += v[j].y * w12[s];
          }
        }
      }
    }
#pragma unroll
    for (int s = 0; s < 4; ++s) {
      *(float2*)&red[((size_t)(0 + s) * 8 + wv) * 130 + 2 * l] =
          make_float2(ax[s].x + ah[s].x, ax[s].y + ah[s].y);
      *(float2*)&red[((size_t)(4 + s) * 8 + wv) * 130 + 2 * l] =
          make_float2(ax[4 + s].x + ah[4 + s].x, ax[4 + s].y + ah[4 + s].y);
      *(float2*)&red[((size_t)(8 + s) * 8 + wv) * 130 + 2 * l] = ax[8 + s];
      *(float2*)&red[((size_t)(12 + s) * 8 + wv) * 130 + 2 * l] = ah[8 + s];
    }
    __syncthreads();
    float rp = 0, zp = 0, xnp = 0, hnp = 0;
#pragma unroll
    for (int w8 = 0; w8 < 8; ++w8) {
      rp  += red[((size_t)(0 + qg) * 8 + w8) * 130 + rr];
      zp  += red[((size_t)(4 + qg) * 8 + w8) * 130 + rr];
      xnp += red[((size_t)(8 + qg) * 8 + w8) * 130 + rr];
      hnp += red[((size_t)(12 + qg) * 8 + w8) * 130 + rr];
    }
    const float r = sigmoidf_(rp + bihs[0 + qg] + bhhs[0 + qg]);
    const float z = sigmoidf_(zp + bihs[4 + qg] + bhhs[4 + qg]);
    const float n = tanhf(xnp + bihs[8 + qg] + r * (hnp + bhhs[8 + qg]));
    const float hnew = (1.0f - z) * n + z * hprev;
    cohst1(big + (size_t)t * SLICE + og, hnew);
    asm volatile("s_waitcnt vmcnt(0)" ::: "memory");
    __syncthreads();
    if (tid == 0) fpost(gf, ng, (unsigned)(t + 1));
    if (t + 1 < NL) {
      const float* const xp = big + (size_t)(t + 2) * SLICE + boff;
#pragma unroll
      for (int s = 0; s < 12; ++s) ax[s] = make_float2(0.0f, 0.0f);
      for (int bq = 0; bq < 4; ++bq) {
        const int kb = k0 + bq * 16;
        float2 v[16];
#pragma unroll
        for (int j = 0; j < 16; ++j) v[j] = cohld2(xp + (size_t)(kb + j) * 256);
#pragma unroll
        for (int j = 0; j < 16; ++j) {
          const float4* const wr = (const float4*)(wxT + (size_t)(kb + j) * 16);
          float w12[12];
          *(float4*)&w12[0] = wr[0];
          *(float4*)&w12[4] = wr[1];
          *(float4*)&w12[8] = wr[2];
#pragma unroll
          for (int s = 0; s < 12; ++s) {
            ax[s].x += v[j].x * w12[s];
            ax[s].y += v[j].y * w12[s];
          }
        }
      }
    }
    asm volatile("" ::: "memory");
  }
}

// ---- attn1 / attn2 (fp32, prior dispatches -> boundary invalidate ok) ----
__global__ __launch_bounds__(256) void attn1_kernel(float* __restrict__ ws) {
  const int l = blockIdx.x, tid = threadIdx.x;
  const float* const sl = ws + BIG_OFF + (size_t)l * SLICE + tid;
  const float* const vtt = ws + VT_OFF + tid;
  float acc = 0.0f;
#pragma unroll 8
  for (int k = 0; k < 512; ++k)
    acc += sl[(size_t)k * 256] * vtt[(size_t)k * 256];
  ws[LG_OFF + (size_t)l * 256 + tid] = acc;
}

__global__ __launch_bounds__(256) void attn2_kernel(float* __restrict__ ws) {
  __shared__ float red[8];
  const int b = blockIdx.x, tid = threadIdx.x;
  const float v = (tid < NL) ? ws[LG_OFF + (size_t)tid * 256 + b] : -3.0e38f;
  float m = v;
  for (int off = 32; off > 0; off >>= 1) m = fmaxf(m, __shfl_xor(m, off));
  if ((tid & 63) == 0) red[tid >> 6] = m;
  __syncthreads();
  m = fmaxf(fmaxf(red[0], red[1]), fmaxf(red[2], red[3]));
  const float e = (tid < NL) ? expf(v - m) : 0.0f;
  float s = e;
  for (int off = 32; off > 0; off >>= 1) s += __shfl_xor(s, off);
  __syncthreads();
  if ((tid & 63) == 0) red[4 + (tid >> 6)] = s;
  __syncthreads();
  s = red[4] + red[5] + red[6] + red[7];
  if (tid < NL) ws[ATT_OFF + (size_t)tid * 256 + b] = e / s;
}

// AUGRU dot (fp16). Activations at k-pair kp0+.. in [0,256); weight row
// offset WOFF (256 for x-part, 0 for h-part). DEPTH = loads in flight.
template <bool COH, int NQ, int SOFF, int WOFF, int DEPTH>
__device__ __forceinline__ void adot(const float* ap, const unsigned* wT24,
                                     int kp0, float* acc) {
  for (int g = 0; g < 32 / DEPTH; ++g) {
    const int kb = kp0 + g * DEPTH;
    float va[DEPTH], vb[DEPTH];
#pragma unroll
    for (int j = 0; j < DEPTH; ++j) {
      const float* p0 = ap + (size_t)(2 * (kb + j)) * 256;
      if (COH) { va[j] = cohld1(p0); vb[j] = cohld1(p0 + 256); }
      else     { va[j] = p0[0]; vb[j] = p0[256]; }
    }
#pragma unroll
    for (int j = 0; j < DEPTH; ++j) {
      const h2 r = pkh(va[j], vb[j]);
      const uint4* wq = (const uint4*)(wT24 + (size_t)(WOFF + kb + j) * 24) + SOFF;
#pragma unroll
      for (int q = 0; q < NQ; ++q) {
        const uint4 qq = wq[q];
        acc[4 * q + 0] = fd2(qq.x, r, acc[4 * q + 0]);
        acc[4 * q + 1] = fd2(qq.y, r, acc[4 * q + 1]);
        acc[4 * q + 2] = fd2(qq.z, r, acc[4 * q + 2]);
        acc[4 * q + 3] = fd2(qq.w, r, acc[4 * q + 3]);
      }
    }
  }
}

// ---- persistent AUGRU: fp16 dots; h_aug in dead BIG slices (L2 h-dot) ----
__global__ __launch_bounds__(512) void augru_kernel(const float* __restrict__ rw,
                                                    const float* __restrict__ rbias,
                                                    const float* __restrict__ uw,
                                                    const float* __restrict__ ubias,
                                                    const float* __restrict__ hw,
                                                    const float* __restrict__ hbias,
                                                    float* __restrict__ ws,
                                                    float* __restrict__ out) {
  __shared__ unsigned wT[512 * 24];   // [kp][24] half2-pairs: slot m*8+c
  __shared__ float red[24 * 8 * 66];
  __shared__ float rbs[8], ubs[8], hbs[8];

  const int rg = blockIdx.x >> 6;
  const int cg = blockIdx.x & 63;
  const int r0 = rg << 6, c0 = cg << 3;
  const int tid = threadIdx.x;

  for (int i = tid; i < 512 * 24; i += 512) {
    const int kp = i / 24, s = i % 24;
    const int m = s >> 3, c = s & 7;
    const float* const wm = (m == 0) ? rw : (m == 1) ? uw : hw;
    wT[i] = pk2(wm[(size_t)(c0 + c) * 1024 + 2 * kp],
                wm[(size_t)(c0 + c) * 1024 + 2 * kp + 1]);
  }
  if (tid < 8) {
    rbs[tid] = rbias[c0 + tid];
    ubs[tid] = ubias[c0 + tid];
    hbs[tid] = hbias[c0 + tid];
  }
  __syncthreads();

  float* const big = ws + BIG_OFF;
  float* const hrg = ws + HR_OFF;
  const float* const att = ws + ATT_OFF;
  unsigned* const fbase = (unsigned*)(ws + FLAGS_OFF);
  unsigned* const af1 = fbase + (size_t)(256 + (rg << 6)) * FSTRIDE;
  unsigned* const af2 = fbase + (size_t)(512 + (rg << 6)) * FSTRIDE;

  const int wv = tid >> 6, l = tid & 63;
  const int kp0 = wv << 5;
  const int boff = r0 + l;
  const int cq = tid >> 6;
  const int rr = tid & 63;
  const size_t og = (size_t)(c0 + cq) * 256 + r0 + rr;

  // prologue: x-dot t=0 (sseqT[0]; sc1 loads keep big slices L2-virgin)
  float ax[24];
#pragma unroll
  for (int s = 0; s < 24; ++s) ax[s] = 0.0f;
  adot<true, 6, 0, 256, 8>(big + boff, wT, kp0, ax);

  for (int t = 0; t < NL; ++t) {
    if (t > 0) {
      if (wv == 0) gwait64(af2, (unsigned)t);
      __syncthreads();
    }
    // h source: t=0 -> slice 199 (GRU final); t=1 -> slice 200; else t-1.
    const float* const hsrc =
        big + ((t == 0) ? 199ul : (t == 1) ? 200ul : (size_t)(t - 1)) * SLICE;
    const float hcur = hsrc[og];
    float ah[16];
#pragma unroll
    for (int s = 0; s < 16; ++s) ah[s] = 0.0f;
    adot<false, 4, 0, 0, 8>(hsrc + boff, wT, kp0, ah);
#pragma unroll
    for (int c = 0; c < 8; ++c) {
      red[((size_t)(0 + c) * 8 + wv) * 66 + l] = ax[c] + ah[c];
      red[((size_t)(8 + c) * 8 + wv) * 66 + l] = ax[8 + c] + ah[8 + c];
      red[((size_t)(16 + c) * 8 + wv) * 66 + l] = ax[16 + c];
    }
    __syncthreads();
    float rp = 0, up = 0, xhp = 0;
#pragma unroll
    for (int w8 = 0; w8 < 8; ++w8) {
      rp  += red[((size_t)(0 + cq) * 8 + w8) * 66 + rr];
      up  += red[((size_t)(8 + cq) * 8 + w8) * 66 + rr];
      xhp += red[((size_t)(16 + cq) * 8 + w8) * 66 + rr];
    }
    const float rgate = sigmoidf_(rp + rbs[cq]);
    const float ug = sigmoidf_(up + ubs[cq]);
    cohst1(hrg + og, rgate * hcur);
    asm volatile("s_waitcnt vmcnt(0)" ::: "memory");
    __syncthreads();
    if (tid == 0) fpost(af1, cg, (unsigned)(t + 1));
    // pipelined x-dot for t+1 inside the af1 window (sc1 loads)
    if (t + 1 < NL) {
#pragma unroll
      for (int s = 0; s < 24; ++s) ax[s] = 0.0f;
      adot<true, 6, 0, 256, 8>(big + (size_t)(t + 1) * SLICE + boff, wT, kp0, ax);
    }
    asm volatile("" ::: "memory");
    if (wv == 0) gwait64(af1, (unsigned)(t + 1));
    __syncthreads();
    // phase2: hhat (hr via sc1, 16-deep batches)
    float ahh[8];
#pragma unroll
    for (int s = 0; s < 8; ++s) ahh[s] = 0.0f;
    adot<true, 2, 4, 0, 16>(hrg + boff, wT, kp0, ahh);
#pragma unroll
    for (int c = 0; c < 8; ++c)
      red[((size_t)c * 8 + wv) * 66 + l] = ahh[c];
    __syncthreads();
    float hhp = 0;
#pragma unroll
    for (int w8 = 0; w8 < 8; ++w8)
      hhp += red[((size_t)cq * 8 + w8) * 66 + rr];
    const float hh = tanhf(hhp + xhp + hbs[cq]);
    const float av = att[(size_t)t * 256 + r0 + rr];
    const float u = av * ug;
    const float hn = (1.0f - u) * hcur + u * hh;
    if (t == NL - 1) {
      out[(size_t)(r0 + rr) * 512 + c0 + cq] = hn;
    } else {
      float* const hdst = big + ((t == 0) ? 200ul : (size_t)t) * SLICE;
      cohst1(hdst + og, hn);
    }
    asm volatile("s_waitcnt vmcnt(0)" ::: "memory");
    __syncthreads();
    if (tid == 0) fpost(af2, cg, (unsigned)(t + 1));
  }
}

extern "C" void kernel_launch(void* const* d_in, const int* in_sizes, int n_in,
                              void* d_out, int out_size, void* d_ws, size_t ws_size,
                              hipStream_t stream) {
  (void)in_sizes; (void)n_in; (void)out_size; (void)ws_size;
  const float* session = (const float*)d_in[0];
  const float* target  = (const float*)d_in[1];
  const float* w       = (const float*)d_in[2];
  const float* wih     = (const float*)d_in[3];
  const float* whh     = (const float*)d_in[4];
  const float* bih     = (const float*)d_in[5];
  const float* bhh     = (const float*)d_in[6];
  const float* rw      = (const float*)d_in[7];
  const float* rb      = (const float*)d_in[8];
  const float* uw      = (const float*)d_in[9];
  const float* ub      = (const float*)d_in[10];
  const float* hw      = (const float*)d_in[11];
  const float* hb      = (const float*)d_in[12];
  float* ws  = (float*)d_ws;
  float* out = (float*)d_out;

  hipLaunchKernelGGL(init_kernel, dim3(4), dim3(256), 0, stream, ws);
  hipLaunchKernelGGL(transpose_kernel, dim3(1600, 4), dim3(256), 0, stream, session, ws);
  hipLaunchKernelGGL(vt_kernel, dim3(256), dim3(256), 0, stream, w, target, ws);
  hipLaunchKernelGGL(gru_kernel, dim3(256), dim3(512), 0, stream,
                     wih, whh, bih, bhh, ws);
  hipLaunchKernelGGL(attn1_kernel, dim3(200), dim3(256), 0, stream, ws);
  hipLaunchKernelGGL(attn2_kernel, dim3(256), dim3(256), 0, stream, ws);
  hipLaunchKernelGGL(augru_kernel, dim3(256), dim3(512), 0, stream,
                     rw, rb, uw, ub, hw, hb, ws, out);
}

// Round 16
// 6925.032 us; speedup vs baseline: 1.0462x; 1.0049x over previous
//
#include <hip/hip_runtime.h>
#include <math.h>

#define NL 200
#define SLICE 131072ul  // 512 k * 256 b floats

// ---- workspace layout (float offsets), activations stored [k][b] ----
// BIG[201][512][256]: slice u+1 = sessionT[u]; GRU writes h_t = sseqT[t] slice t.
// AUGRU reuses dead slices: h_aug[0] -> slice 200, h_aug[t>=1] -> slice t.
#define BIG_OFF   0ul
#define LG_OFF    26345472ul   // logits [200][256]
#define ATT_OFF   26396672ul   // att    [200][256]
#define VT_OFF    26447872ul   // vtT    [512][256]
#define HR_OFF    26841088ul   // r*h [512][256] (sc1 both ways; address-reused)
#define FLAGS_OFF 26972160ul   // u32 flags, ONE PER 64B LINE (stride 16):
                               // gf[2][128] @slot 0, af1[4][64] @256, af2[4][64] @512
#define FSTRIDE   16           // u32 per flag slot (64B line)

typedef __attribute__((ext_vector_type(2))) __fp16 h2;  // matches fdot2 builtin type

__device__ __forceinline__ float sigmoidf_(float x) { return 1.0f / (1.0f + expf(-x)); }

// pack two f32 -> half2, RNE
__device__ __forceinline__ unsigned pk2(float a, float b) {
  union { h2 h; unsigned u; } x;
  x.h.x = (__fp16)a; x.h.y = (__fp16)b;
  return x.u;
}
__device__ __forceinline__ h2 pkh(float a, float b) {
  h2 r; r.x = (__fp16)a; r.y = (__fp16)b; return r;
}
__device__ __forceinline__ float fd2(unsigned w, h2 a, float c) {
  union { unsigned u; h2 h; } x; x.u = w;
  return __builtin_amdgcn_fdot2(a, x.h, c, false);
}

// ---- LLC-direct (sc1) accessors: relaxed agent atomics, no fences ----
__device__ __forceinline__ float cohld1(const float* p) {
  return __hip_atomic_load(p, __ATOMIC_RELAXED, __HIP_MEMORY_SCOPE_AGENT);
}
__device__ __forceinline__ float2 cohld2(const float* p) {
  union { double d; float2 f; } u;
  u.d = __hip_atomic_load((const double*)p, __ATOMIC_RELAXED, __HIP_MEMORY_SCOPE_AGENT);
  return u.f;
}
__device__ __forceinline__ void cohst1(float* p, float v) {
  __hip_atomic_store(p, v, __ATOMIC_RELAXED, __HIP_MEMORY_SCOPE_AGENT);
}

// ---- PER-WAVE wait: lane i polls flag slot base + (i & mask); the wave
// proceeds when every lane's flag reached val. Only this wave's producer
// subset gates this wave -> skew overlaps with other waves' compute. ----
__device__ __forceinline__ void wwait(const unsigned* f, int base, unsigned val, int mask) {
  const unsigned* const p = f + (size_t)(base + (threadIdx.x & mask)) * FSTRIDE;
  if (__hip_atomic_load(p, __ATOMIC_RELAXED, __HIP_MEMORY_SCOPE_AGENT) >= val) {
    asm volatile("" ::: "memory");
    return;
  }
  int guard = 0;
  while (__hip_atomic_load(p, __ATOMIC_RELAXED, __HIP_MEMORY_SCOPE_AGENT) < val) {
    __builtin_amdgcn_s_sleep(1);
    if (++guard > (1 << 22)) break;  // deadlock escape
  }
  asm volatile("" ::: "memory");
}
__device__ __forceinline__ void fpost(unsigned* f, int slot, unsigned val) {
  __hip_atomic_store(f + (size_t)slot * FSTRIDE, val, __ATOMIC_RELAXED, __HIP_MEMORY_SCOPE_AGENT);
}

__global__ void init_kernel(float* __restrict__ ws) {
  unsigned* const fl = (unsigned*)(ws + FLAGS_OFF);
  const int i = blockIdx.x * 256 + threadIdx.x;
  for (int j = i; j < 768 * FSTRIDE; j += 4 * 256) fl[j] = 0u;
}

// ---- transpose session -> BIG slices 1..200 as [k][b] (sc1 stores) ----
__global__ __launch_bounds__(256) void transpose_kernel(const float* __restrict__ in,
                                                        float* __restrict__ ws) {
  __shared__ float tile[64][65];
  const int tx = threadIdx.x & 63, ty = threadIdx.x >> 6;
  const size_t tk0 = (size_t)blockIdx.x * 64;
  const int b0 = blockIdx.y * 64;
#pragma unroll
  for (int r = 0; r < 16; ++r) {
    const int bb = ty + 4 * r;
    tile[bb][tx] = in[(size_t)(b0 + bb) * 102400 + tk0 + tx];
  }
  __syncthreads();
  float* const big1 = ws + BIG_OFF + SLICE;
#pragma unroll
  for (int r = 0; r < 16; ++r) {
    const int kk = ty + 4 * r;
    cohst1(big1 + (tk0 + kk) * 256 + b0 + tx, tile[tx][kk]);
  }
}

// ---- vtT[d][b] = sum_e w[d,e] * target[b,e] (fp32) ----
__global__ __launch_bounds__(256) void vt_kernel(const float* __restrict__ w,
                                                 const float* __restrict__ tgt,
                                                 float* __restrict__ ws) {
  __shared__ float t_s[512];
  const int b = blockIdx.x, tid = threadIdx.x;
  for (int i = tid; i < 512; i += 256) t_s[i] = tgt[(size_t)b * 512 + i];
  __syncthreads();
  const int wv = tid >> 6, lane = tid & 63;
  for (int d = wv; d < 512; d += 4) {
    const float* const wr = w + (size_t)d * 512;
    const float4 a  = *(const float4*)(wr + lane * 8);
    const float4 a2 = *(const float4*)(wr + lane * 8 + 4);
    float s = a.x * t_s[lane * 8 + 0] + a.y * t_s[lane * 8 + 1] +
              a.z * t_s[lane * 8 + 2] + a.w * t_s[lane * 8 + 3] +
              a2.x * t_s[lane * 8 + 4] + a2.y * t_s[lane * 8 + 5] +
              a2.z * t_s[lane * 8 + 6] + a2.w * t_s[lane * 8 + 7];
    for (int off = 32; off > 0; off >>= 1) s += __shfl_xor(s, off);
    if (lane == 0) ws[VT_OFF + (size_t)d * 256 + b] = s;
  }
}

// ---- persistent GRU: fp32; per-wave producer waits (16 flags/wave) ----
__global__ __launch_bounds__(512) void gru_kernel(const float* __restrict__ wih,
                                                  const float* __restrict__ whh,
                                                  const float* __restrict__ bih,
                                                  const float* __restrict__ bhh,
                                                  float* __restrict__ ws) {
  __shared__ float wxT[512 * 16];
  __shared__ float whT[512 * 16];
  __shared__ float red[16 * 8 * 130];
  __shared__ float bihs[12], bhhs[12];

  const int bg = blockIdx.x >> 7;
  const int ng = blockIdx.x & 127;
  const int b0 = bg << 7, c0 = ng << 2;
  const int tid = threadIdx.x;

  for (int i = tid; i < 512 * 16; i += 512) {
    const int k = i >> 4, s = i & 15;
    if (s < 12) {
      const int grow = ((s >> 2) << 9) + c0 + (s & 3);
      wxT[i] = wih[(size_t)grow * 512 + k];
      whT[i] = whh[(size_t)grow * 512 + k];
    }
  }
  if (tid < 12) {
    const int grow = ((tid >> 2) << 9) + c0 + (tid & 3);
    bihs[tid] = bih[grow];
    bhhs[tid] = bhh[grow];
  }
  __syncthreads();

  float* const big = ws + BIG_OFF;
  unsigned* const gf = (unsigned*)(ws + FLAGS_OFF) + (size_t)(bg << 7) * FSTRIDE;

  const int wv = tid >> 6, l = tid & 63;
  const int k0 = wv << 6;
  const int boff = b0 + 2 * l;
  const int qg = tid >> 7;
  const int rr = tid & 127;
  const size_t og = (size_t)(c0 + qg) * 256 + b0 + rr;

  float2 ax[12];
#pragma unroll
  for (int s = 0; s < 12; ++s) ax[s] = make_float2(0.0f, 0.0f);
  {
    const float* const xp = big + 1ul * SLICE + boff;
    for (int bq = 0; bq < 4; ++bq) {
      const int kb = k0 + bq * 16;
      float2 v[16];
#pragma unroll
      for (int j = 0; j < 16; ++j) v[j] = cohld2(xp + (size_t)(kb + j) * 256);
#pragma unroll
      for (int j = 0; j < 16; ++j) {
        const float4* const wr = (const float4*)(wxT + (size_t)(kb + j) * 16);
        float w12[12];
        *(float4*)&w12[0] = wr[0];
        *(float4*)&w12[4] = wr[1];
        *(float4*)&w12[8] = wr[2];
#pragma unroll
        for (int s = 0; s < 12; ++s) {
          ax[s].x += v[j].x * w12[s];
          ax[s].y += v[j].y * w12[s];
        }
      }
    }
  }

  for (int t = 0; t < NL; ++t) {
    // per-wave wait: this wave's h-dot k-range [64wv,64wv+64) was produced
    // by col-group blocks ng' = 16wv..16wv+15 of this batch half.
    if (t > 0) wwait(gf, wv << 4, (unsigned)t, 15);
    float2 ah[12];
#pragma unroll
    for (int s = 0; s < 12; ++s) ah[s] = make_float2(0.0f, 0.0f);
    float hprev = 0.0f;
    if (t > 0) {
      const float* const hp = big + (size_t)(t - 1) * SLICE + boff;
      hprev = big[(size_t)(t - 1) * SLICE + og];  // own cols: self-produced
      for (int bq = 0; bq < 4; ++bq) {
        const int kb = k0 + bq * 16;
        float2 v[16];
#pragma unroll
        for (int j = 0; j < 16; ++j) v[j] = *(const float2*)(hp + (size_t)(kb + j) * 256);
#pragma unroll
        for (int j = 0; j < 16; ++j) {
          const float4* const wr = (const float4*)(whT + (size_t)(kb + j) * 16);
          float w12[12];
          *(float4*)&w12[0] = wr[0];
          *(float4*)&w12[4] = wr[1];
          *(float4*)&w12[8] = wr[2];
#pragma unroll
          for (int s = 0; s < 12; ++s) {
            ah[s].x += v[j].x * w12[s];
            ah[s].y += v[j].y * w12[s];
          }
        }
      }
    }
#pragma unroll
    for (int s = 0; s < 4; ++s) {
      *(float2*)&red[((size_t)(0 + s) * 8 + wv) * 130 + 2 * l] =
          make_float2(ax[s].x + ah[s].x, ax[s].y + ah[s].y);
      *(float2*)&red[((size_t)(4 + s) * 8 + wv) * 130 + 2 * l] =
          make_float2(ax[4 + s].x + ah[4 + s].x, ax[4 + s].y + ah[4 + s].y);
      *(float2*)&red[((size_t)(8 + s) * 8 + wv) * 130 + 2 * l] = ax[8 + s];
      *(float2*)&red[((size_t)(12 + s) * 8 + wv) * 130 + 2 * l] = ah[8 + s];
    }
    __syncthreads();  // block-wide join (replaces post-wait barrier too)
    float rp = 0, zp = 0, xnp = 0, hnp = 0;
#pragma unroll
    for (int w8 = 0; w8 < 8; ++w8) {
      rp  += red[((size_t)(0 + qg) * 8 + w8) * 130 + rr];
      zp  += red[((size_t)(4 + qg) * 8 + w8) * 130 + rr];
      xnp += red[((size_t)(8 + qg) * 8 + w8) * 130 + rr];
      hnp += red[((size_t)(12 + qg) * 8 + w8) * 130 + rr];
    }
    const float r = sigmoidf_(rp + bihs[0 + qg] + bhhs[0 + qg]);
    const float z = sigmoidf_(zp + bihs[4 + qg] + bhhs[4 + qg]);
    const float n = tanhf(xnp + bihs[8 + qg] + r * (hnp + bhhs[8 + qg]));
    const float hnew = (1.0f - z) * n + z * hprev;
    cohst1(big + (size_t)t * SLICE + og, hnew);
    asm volatile("s_waitcnt vmcnt(0)" ::: "memory");
    __syncthreads();
    if (tid == 0) fpost(gf, ng, (unsigned)(t + 1));
    if (t + 1 < NL) {
      const float* const xp = big + (size_t)(t + 2) * SLICE + boff;
#pragma unroll
      for (int s = 0; s < 12; ++s) ax[s] = make_float2(0.0f, 0.0f);
      for (int bq = 0; bq < 4; ++bq) {
        const int kb = k0 + bq * 16;
        float2 v[16];
#pragma unroll
        for (int j = 0; j < 16; ++j) v[j] = cohld2(xp + (size_t)(kb + j) * 256);
#pragma unroll
        for (int j = 0; j < 16; ++j) {
          const float4* const wr = (const float4*)(wxT + (size_t)(kb + j) * 16);
          float w12[12];
          *(float4*)&w12[0] = wr[0];
          *(float4*)&w12[4] = wr[1];
          *(float4*)&w12[8] = wr[2];
#pragma unroll
          for (int s = 0; s < 12; ++s) {
            ax[s].x += v[j].x * w12[s];
            ax[s].y += v[j].y * w12[s];
          }
        }
      }
    }
    asm volatile("" ::: "memory");
  }
}

// ---- attn1 / attn2 (fp32, prior dispatches -> boundary invalidate ok) ----
__global__ __launch_bounds__(256) void attn1_kernel(float* __restrict__ ws) {
  const int l = blockIdx.x, tid = threadIdx.x;
  const float* const sl = ws + BIG_OFF + (size_t)l * SLICE + tid;
  const float* const vtt = ws + VT_OFF + tid;
  float acc = 0.0f;
#pragma unroll 8
  for (int k = 0; k < 512; ++k)
    acc += sl[(size_t)k * 256] * vtt[(size_t)k * 256];
  ws[LG_OFF + (size_t)l * 256 + tid] = acc;
}

__global__ __launch_bounds__(256) void attn2_kernel(float* __restrict__ ws) {
  __shared__ float red[8];
  const int b = blockIdx.x, tid = threadIdx.x;
  const float v = (tid < NL) ? ws[LG_OFF + (size_t)tid * 256 + b] : -3.0e38f;
  float m = v;
  for (int off = 32; off > 0; off >>= 1) m = fmaxf(m, __shfl_xor(m, off));
  if ((tid & 63) == 0) red[tid >> 6] = m;
  __syncthreads();
  m = fmaxf(fmaxf(red[0], red[1]), fmaxf(red[2], red[3]));
  const float e = (tid < NL) ? expf(v - m) : 0.0f;
  float s = e;
  for (int off = 32; off > 0; off >>= 1) s += __shfl_xor(s, off);
  __syncthreads();
  if ((tid & 63) == 0) red[4 + (tid >> 6)] = s;
  __syncthreads();
  s = red[4] + red[5] + red[6] + red[7];
  if (tid < NL) ws[ATT_OFF + (size_t)tid * 256 + b] = e / s;
}

// AUGRU dot (fp16). Activations at k-pair kp0+.. in [0,256); weight row
// offset WOFF (256 for x-part, 0 for h-part). DEPTH = loads in flight.
template <bool COH, int NQ, int SOFF, int WOFF, int DEPTH>
__device__ __forceinline__ void adot(const float* ap, const unsigned* wT24,
                                     int kp0, float* acc) {
  for (int g = 0; g < 32 / DEPTH; ++g) {
    const int kb = kp0 + g * DEPTH;
    float va[DEPTH], vb[DEPTH];
#pragma unroll
    for (int j = 0; j < DEPTH; ++j) {
      const float* p0 = ap + (size_t)(2 * (kb + j)) * 256;
      if (COH) { va[j] = cohld1(p0); vb[j] = cohld1(p0 + 256); }
      else     { va[j] = p0[0]; vb[j] = p0[256]; }
    }
#pragma unroll
    for (int j = 0; j < DEPTH; ++j) {
      const h2 r = pkh(va[j], vb[j]);
      const uint4* wq = (const uint4*)(wT24 + (size_t)(WOFF + kb + j) * 24) + SOFF;
#pragma unroll
      for (int q = 0; q < NQ; ++q) {
        const uint4 qq = wq[q];
        acc[4 * q + 0] = fd2(qq.x, r, acc[4 * q + 0]);
        acc[4 * q + 1] = fd2(qq.y, r, acc[4 * q + 1]);
        acc[4 * q + 2] = fd2(qq.z, r, acc[4 * q + 2]);
        acc[4 * q + 3] = fd2(qq.w, r, acc[4 * q + 3]);
      }
    }
  }
}

// ---- persistent AUGRU: fp16 dots; per-wave producer waits (8 flags/wave) ----
__global__ __launch_bounds__(512) void augru_kernel(const float* __restrict__ rw,
                                                    const float* __restrict__ rbias,
                                                    const float* __restrict__ uw,
                                                    const float* __restrict__ ubias,
                                                    const float* __restrict__ hw,
                                                    const float* __restrict__ hbias,
                                                    float* __restrict__ ws,
                                                    float* __restrict__ out) {
  __shared__ unsigned wT[512 * 24];   // [kp][24] half2-pairs: slot m*8+c
  __shared__ float red[24 * 8 * 66];
  __shared__ float rbs[8], ubs[8], hbs[8];

  const int rg = blockIdx.x >> 6;
  const int cg = blockIdx.x & 63;
  const int r0 = rg << 6, c0 = cg << 3;
  const int tid = threadIdx.x;

  for (int i = tid; i < 512 * 24; i += 512) {
    const int kp = i / 24, s = i % 24;
    const int m = s >> 3, c = s & 7;
    const float* const wm = (m == 0) ? rw : (m == 1) ? uw : hw;
    wT[i] = pk2(wm[(size_t)(c0 + c) * 1024 + 2 * kp],
                wm[(size_t)(c0 + c) * 1024 + 2 * kp + 1]);
  }
  if (tid < 8) {
    rbs[tid] = rbias[c0 + tid];
    ubs[tid] = ubias[c0 + tid];
    hbs[tid] = hbias[c0 + tid];
  }
  __syncthreads();

  float* const big = ws + BIG_OFF;
  float* const hrg = ws + HR_OFF;
  const float* const att = ws + ATT_OFF;
  unsigned* const fbase = (unsigned*)(ws + FLAGS_OFF);
  unsigned* const af1 = fbase + (size_t)(256 + (rg << 6)) * FSTRIDE;
  unsigned* const af2 = fbase + (size_t)(512 + (rg << 6)) * FSTRIDE;

  const int wv = tid >> 6, l = tid & 63;
  const int kp0 = wv << 5;
  const int boff = r0 + l;
  const int cq = tid >> 6;
  const int rr = tid & 63;
  const size_t og = (size_t)(c0 + cq) * 256 + r0 + rr;

  // prologue: x-dot t=0 (sseqT[0]; sc1 loads keep big slices L2-virgin)
  float ax[24];
#pragma unroll
  for (int s = 0; s < 24; ++s) ax[s] = 0.0f;
  adot<true, 6, 0, 256, 8>(big + boff, wT, kp0, ax);

  for (int t = 0; t < NL; ++t) {
    // per-wave wait: h-dot k-range [64wv,64wv+64) of h_aug[t-1] was produced
    // by col-groups cg' = 8wv..8wv+7 of this row-group (flags af2).
    if (t > 0) wwait(af2, wv << 3, (unsigned)t, 7);
    // h source: t=0 -> slice 199 (GRU final); t=1 -> slice 200; else t-1.
    const float* const hsrc =
        big + ((t == 0) ? 199ul : (t == 1) ? 200ul : (size_t)(t - 1)) * SLICE;
    const float hcur = hsrc[og];  // own cols: self-produced
    float ah[16];
#pragma unroll
    for (int s = 0; s < 16; ++s) ah[s] = 0.0f;
    adot<false, 4, 0, 0, 8>(hsrc + boff, wT, kp0, ah);
#pragma unroll
    for (int c = 0; c < 8; ++c) {
      red[((size_t)(0 + c) * 8 + wv) * 66 + l] = ax[c] + ah[c];
      red[((size_t)(8 + c) * 8 + wv) * 66 + l] = ax[8 + c] + ah[8 + c];
      red[((size_t)(16 + c) * 8 + wv) * 66 + l] = ax[16 + c];
    }
    __syncthreads();  // block-wide join
    float rp = 0, up = 0, xhp = 0;
#pragma unroll
    for (int w8 = 0; w8 < 8; ++w8) {
      rp  += red[((size_t)(0 + cq) * 8 + w8) * 66 + rr];
      up  += red[((size_t)(8 + cq) * 8 + w8) * 66 + rr];
      xhp += red[((size_t)(16 + cq) * 8 + w8) * 66 + rr];
    }
    const float rgate = sigmoidf_(rp + rbs[cq]);
    const float ug = sigmoidf_(up + ubs[cq]);
    cohst1(hrg + og, rgate * hcur);
    asm volatile("s_waitcnt vmcnt(0)" ::: "memory");
    __syncthreads();
    if (tid == 0) fpost(af1, cg, (unsigned)(t + 1));
    // pipelined x-dot for t+1 inside the af1 window (sc1 loads)
    if (t + 1 < NL) {
#pragma unroll
      for (int s = 0; s < 24; ++s) ax[s] = 0.0f;
      adot<true, 6, 0, 256, 8>(big + (size_t)(t + 1) * SLICE + boff, wT, kp0, ax);
    }
    asm volatile("" ::: "memory");
    // per-wave wait: hr-dot k-range produced by col-groups 8wv..8wv+7 (af1).
    wwait(af1, wv << 3, (unsigned)(t + 1), 7);
    // phase2: hhat (hr via sc1, 16-deep batches)
    float ahh[8];
#pragma unroll
    for (int s = 0; s < 8; ++s) ahh[s] = 0.0f;
    adot<true, 2, 4, 0, 16>(hrg + boff, wT, kp0, ahh);
#pragma unroll
    for (int c = 0; c < 8; ++c)
      red[((size_t)c * 8 + wv) * 66 + l] = ahh[c];
    __syncthreads();
    float hhp = 0;
#pragma unroll
    for (int w8 = 0; w8 < 8; ++w8)
      hhp += red[((size_t)cq * 8 + w8) * 66 + rr];
    const float hh = tanhf(hhp + xhp + hbs[cq]);
    const float av = att[(size_t)t * 256 + r0 + rr];
    const float u = av * ug;
    const float hn = (1.0f - u) * hcur + u * hh;
    if (t == NL - 1) {
      out[(size_t)(r0 + rr) * 512 + c0 + cq] = hn;
    } else {
      float* const hdst = big + ((t == 0) ? 200ul : (size_t)t) * SLICE;
      cohst1(hdst + og, hn);
    }
    asm volatile("s_waitcnt vmcnt(0)" ::: "memory");
    __syncthreads();
    if (tid == 0) fpost(af2, cg, (unsigned)(t + 1));
  }
}

extern "C" void kernel_launch(void* const* d_in, const int* in_sizes, int n_in,
                              void* d_out, int out_size, void* d_ws, size_t ws_size,
                              hipStream_t stream) {
  (void)in_sizes; (void)n_in; (void)out_size; (void)ws_size;
  const float* session = (const float*)d_in[0];
  const float* target  = (const float*)d_in[1];
  const float* w       = (const float*)d_in[2];
  const float* wih     = (const float*)d_in[3];
  const float* whh     = (const float*)d_in[4];
  const float* bih     = (const float*)d_in[5];
  const float* bhh     = (const float*)d_in[6];
  const float* rw      = (const float*)d_in[7];
  const float* rb      = (const float*)d_in[8];
  const float* uw      = (const float*)d_in[9];
  const float* ub      = (const float*)d_in[10];
  const float* hw      = (const float*)d_in[11];
  const float* hb      = (const float*)d_in[12];
  float* ws  = (float*)d_ws;
  float* out = (float*)d_out;

  hipLaunchKernelGGL(init_kernel, dim3(4), dim3(256), 0, stream, ws);
  hipLaunchKernelGGL(transpose_kernel, dim3(1600, 4), dim3(256), 0, stream, session, ws);
  hipLaunchKernelGGL(vt_kernel, dim3(256), dim3(256), 0, stream, w, target, ws);
  hipLaunchKernelGGL(gru_kernel, dim3(256), dim3(512), 0, stream,
                     wih, whh, bih, bhh, ws);
  hipLaunchKernelGGL(attn1_kernel, dim3(200), dim3(256), 0, stream, ws);
  hipLaunchKernelGGL(attn2_kernel, dim3(256), dim3(256), 0, stream, ws);
  hipLaunchKernelGGL(augru_kernel, dim3(256), dim3(512), 0, stream,
                     rw, rb, uw, ub, hw, hb, ws, out);
}

// Round 17
// 6097.834 us; speedup vs baseline: 1.1881x; 1.1357x over previous
//
#include <hip/hip_runtime.h>
#include <math.h>

#define NL 200
#define SLICE 131072ul  // 512 k * 256 b floats

// ---- workspace layout (float offsets), activations stored [k][b] ----
// BIG[201][512][256]: slice u+1 = sessionT[u]; GRU writes h_t = sseqT[t] slice t.
// AUGRU reuses dead slices: h_aug[0] -> slice 200, h_aug[t>=1] -> slice t.
#define BIG_OFF   0ul
#define LG_OFF    26345472ul   // logits [200][256]
#define ATT_OFF   26396672ul   // att    [200][256]
#define VT_OFF    26447872ul   // vtT    [512][256]
#define HR_OFF    26841088ul   // r*h [512][256] (sc1 both ways; address-reused)
#define FLAGS_OFF 26972160ul   // u32 flags, ONE PER 64B LINE (stride 16):
                               // gf[2][128] @slot 0, af1[4][64] @256, af2[4][64] @512
#define FSTRIDE   16           // u32 per flag slot (64B line)

typedef __attribute__((ext_vector_type(2))) __fp16 h2;  // matches fdot2 builtin type

__device__ __forceinline__ float sigmoidf_(float x) { return 1.0f / (1.0f + expf(-x)); }

// pack two f32 -> half2, RNE
__device__ __forceinline__ unsigned pk2(float a, float b) {
  union { h2 h; unsigned u; } x;
  x.h.x = (__fp16)a; x.h.y = (__fp16)b;
  return x.u;
}
__device__ __forceinline__ h2 pkh(float a, float b) {
  h2 r; r.x = (__fp16)a; r.y = (__fp16)b; return r;
}
__device__ __forceinline__ float fd2(unsigned w, h2 a, float c) {
  union { unsigned u; h2 h; } x; x.u = w;
  return __builtin_amdgcn_fdot2(a, x.h, c, false);
}

// ---- LLC-direct (sc1) accessors: relaxed agent atomics, no fences ----
__device__ __forceinline__ float cohld1(const float* p) {
  return __hip_atomic_load(p, __ATOMIC_RELAXED, __HIP_MEMORY_SCOPE_AGENT);
}
__device__ __forceinline__ float2 cohld2(const float* p) {
  union { double d; float2 f; } u;
  u.d = __hip_atomic_load((const double*)p, __ATOMIC_RELAXED, __HIP_MEMORY_SCOPE_AGENT);
  return u.f;
}
__device__ __forceinline__ void cohst1(float* p, float v) {
  __hip_atomic_store(p, v, __ATOMIC_RELAXED, __HIP_MEMORY_SCOPE_AGENT);
}

// ---- PER-WAVE wait: lane i polls flag slot base + (i & mask) ----
__device__ __forceinline__ void wwait(const unsigned* f, int base, unsigned val, int mask) {
  const unsigned* const p = f + (size_t)(base + (threadIdx.x & mask)) * FSTRIDE;
  if (__hip_atomic_load(p, __ATOMIC_RELAXED, __HIP_MEMORY_SCOPE_AGENT) >= val) {
    asm volatile("" ::: "memory");
    return;
  }
  int guard = 0;
  while (__hip_atomic_load(p, __ATOMIC_RELAXED, __HIP_MEMORY_SCOPE_AGENT) < val) {
    __builtin_amdgcn_s_sleep(1);
    if (++guard > (1 << 22)) break;  // deadlock escape
  }
  asm volatile("" ::: "memory");
}
__device__ __forceinline__ void fpost(unsigned* f, int slot, unsigned val) {
  __hip_atomic_store(f + (size_t)slot * FSTRIDE, val, __ATOMIC_RELAXED, __HIP_MEMORY_SCOPE_AGENT);
}

__global__ void init_kernel(float* __restrict__ ws) {
  unsigned* const fl = (unsigned*)(ws + FLAGS_OFF);
  const int i = blockIdx.x * 256 + threadIdx.x;
  for (int j = i; j < 768 * FSTRIDE; j += 4 * 256) fl[j] = 0u;
}

// ---- transpose session -> BIG slices 1..200 as [k][b] (sc1 stores) ----
__global__ __launch_bounds__(256) void transpose_kernel(const float* __restrict__ in,
                                                        float* __restrict__ ws) {
  __shared__ float tile[64][65];
  const int tx = threadIdx.x & 63, ty = threadIdx.x >> 6;
  const size_t tk0 = (size_t)blockIdx.x * 64;
  const int b0 = blockIdx.y * 64;
#pragma unroll
  for (int r = 0; r < 16; ++r) {
    const int bb = ty + 4 * r;
    tile[bb][tx] = in[(size_t)(b0 + bb) * 102400 + tk0 + tx];
  }
  __syncthreads();
  float* const big1 = ws + BIG_OFF + SLICE;
#pragma unroll
  for (int r = 0; r < 16; ++r) {
    const int kk = ty + 4 * r;
    cohst1(big1 + (tk0 + kk) * 256 + b0 + tx, tile[tx][kk]);
  }
}

// ---- vtT[d][b] = sum_e w[d,e] * target[b,e] (fp32) ----
__global__ __launch_bounds__(256) void vt_kernel(const float* __restrict__ w,
                                                 const float* __restrict__ tgt,
                                                 float* __restrict__ ws) {
  __shared__ float t_s[512];
  const int b = blockIdx.x, tid = threadIdx.x;
  for (int i = tid; i < 512; i += 256) t_s[i] = tgt[(size_t)b * 512 + i];
  __syncthreads();
  const int wv = tid >> 6, lane = tid & 63;
  for (int d = wv; d < 512; d += 4) {
    const float* const wr = w + (size_t)d * 512;
    const float4 a  = *(const float4*)(wr + lane * 8);
    const float4 a2 = *(const float4*)(wr + lane * 8 + 4);
    float s = a.x * t_s[lane * 8 + 0] + a.y * t_s[lane * 8 + 1] +
              a.z * t_s[lane * 8 + 2] + a.w * t_s[lane * 8 + 3] +
              a2.x * t_s[lane * 8 + 4] + a2.y * t_s[lane * 8 + 5] +
              a2.z * t_s[lane * 8 + 6] + a2.w * t_s[lane * 8 + 7];
    for (int off = 32; off > 0; off >>= 1) s += __shfl_xor(s, off);
    if (lane == 0) ws[VT_OFF + (size_t)d * 256 + b] = s;
  }
}

// GRU fp16 dot: 12 slots x 2 rows. wT16: [kp][16] u32 (12 used).
// ap pre-offset by boff; kp0 in [0,256) (32 k-pairs per wave).
template <bool COH>
__device__ __forceinline__ void gdot12(const float* ap, const unsigned* wT16,
                                       int kp0, float2* acc) {
  for (int g = 0; g < 4; ++g) {
    const int kb = kp0 + g * 8;
    float2 va[8], vb[8];
#pragma unroll
    for (int j = 0; j < 8; ++j) {
      const float* p0 = ap + (size_t)(2 * (kb + j)) * 256;
      if (COH) { va[j] = cohld2(p0); vb[j] = cohld2(p0 + 256); }
      else     { va[j] = *(const float2*)p0; vb[j] = *(const float2*)(p0 + 256); }
    }
#pragma unroll
    for (int j = 0; j < 8; ++j) {
      const h2 r0 = pkh(va[j].x, vb[j].x);   // row A: (act_k, act_{k+1})
      const h2 r1 = pkh(va[j].y, vb[j].y);   // row B
      const uint4* wq = (const uint4*)(wT16 + (size_t)(kb + j) * 16);
      const uint4 q0 = wq[0], q1 = wq[1], q2 = wq[2];
      acc[0].x = fd2(q0.x, r0, acc[0].x);  acc[0].y = fd2(q0.x, r1, acc[0].y);
      acc[1].x = fd2(q0.y, r0, acc[1].x);  acc[1].y = fd2(q0.y, r1, acc[1].y);
      acc[2].x = fd2(q0.z, r0, acc[2].x);  acc[2].y = fd2(q0.z, r1, acc[2].y);
      acc[3].x = fd2(q0.w, r0, acc[3].x);  acc[3].y = fd2(q0.w, r1, acc[3].y);
      acc[4].x = fd2(q1.x, r0, acc[4].x);  acc[4].y = fd2(q1.x, r1, acc[4].y);
      acc[5].x = fd2(q1.y, r0, acc[5].x);  acc[5].y = fd2(q1.y, r1, acc[5].y);
      acc[6].x = fd2(q1.z, r0, acc[6].x);  acc[6].y = fd2(q1.z, r1, acc[6].y);
      acc[7].x = fd2(q1.w, r0, acc[7].x);  acc[7].y = fd2(q1.w, r1, acc[7].y);
      acc[8].x = fd2(q2.x, r0, acc[8].x);  acc[8].y = fd2(q2.x, r1, acc[8].y);
      acc[9].x = fd2(q2.y, r0, acc[9].x);  acc[9].y = fd2(q2.y, r1, acc[9].y);
      acc[10].x = fd2(q2.z, r0, acc[10].x); acc[10].y = fd2(q2.z, r1, acc[10].y);
      acc[11].x = fd2(q2.w, r0, acc[11].x); acc[11].y = fd2(q2.w, r1, acc[11].y);
    }
  }
}

// ---- persistent GRU: fp16 dots; per-wave producer waits (16 flags/wave) ----
__global__ __launch_bounds__(512) void gru_kernel(const float* __restrict__ wih,
                                                  const float* __restrict__ whh,
                                                  const float* __restrict__ bih,
                                                  const float* __restrict__ bhh,
                                                  float* __restrict__ ws) {
  __shared__ unsigned wxT[256 * 16];   // [kp][16] half2-pairs, slots g*4+q (12 used)
  __shared__ unsigned whT[256 * 16];
  __shared__ float red[16 * 8 * 130];
  __shared__ float bihs[12], bhhs[12];

  const int bg = blockIdx.x >> 7;
  const int ng = blockIdx.x & 127;
  const int b0 = bg << 7, c0 = ng << 2;
  const int tid = threadIdx.x;

  for (int i = tid; i < 256 * 16; i += 512) {
    const int kp = i >> 4, s = i & 15;
    if (s < 12) {
      const int grow = ((s >> 2) << 9) + c0 + (s & 3);
      wxT[i] = pk2(wih[(size_t)grow * 512 + 2 * kp], wih[(size_t)grow * 512 + 2 * kp + 1]);
      whT[i] = pk2(whh[(size_t)grow * 512 + 2 * kp], whh[(size_t)grow * 512 + 2 * kp + 1]);
    } else { wxT[i] = 0u; whT[i] = 0u; }
  }
  if (tid < 12) {
    const int grow = ((tid >> 2) << 9) + c0 + (tid & 3);
    bihs[tid] = bih[grow];
    bhhs[tid] = bhh[grow];
  }
  __syncthreads();

  float* const big = ws + BIG_OFF;
  unsigned* const gf = (unsigned*)(ws + FLAGS_OFF) + (size_t)(bg << 7) * FSTRIDE;

  const int wv = tid >> 6, l = tid & 63;
  const int kp0 = wv << 5;              // 32 k-pairs per wave
  const int boff = b0 + 2 * l;          // dot-stage rows 2l,2l+1
  const int qg = tid >> 7;              // gate-stage col
  const int rr = tid & 127;             // gate-stage row
  const size_t og = (size_t)(c0 + qg) * 256 + b0 + rr;

  float2 ax[12];
#pragma unroll
  for (int s = 0; s < 12; ++s) ax[s] = make_float2(0.0f, 0.0f);
  gdot12<true>(big + 1ul * SLICE + boff, wxT, kp0, ax);

  for (int t = 0; t < NL; ++t) {
    // per-wave wait: h-dot k-range [64wv,64wv+64) produced by col-groups
    // ng' = 16wv..16wv+15 of this batch half.
    if (t > 0) wwait(gf, wv << 4, (unsigned)t, 15);
    float2 ah[12];
#pragma unroll
    for (int s = 0; s < 12; ++s) ah[s] = make_float2(0.0f, 0.0f);
    float hprev = 0.0f;
    if (t > 0) {
      hprev = big[(size_t)(t - 1) * SLICE + og];  // own cols: self-produced
      gdot12<false>(big + (size_t)(t - 1) * SLICE + boff, whT, kp0, ah);
    }
#pragma unroll
    for (int s = 0; s < 4; ++s) {
      *(float2*)&red[((size_t)(0 + s) * 8 + wv) * 130 + 2 * l] =
          make_float2(ax[s].x + ah[s].x, ax[s].y + ah[s].y);
      *(float2*)&red[((size_t)(4 + s) * 8 + wv) * 130 + 2 * l] =
          make_float2(ax[4 + s].x + ah[4 + s].x, ax[4 + s].y + ah[4 + s].y);
      *(float2*)&red[((size_t)(8 + s) * 8 + wv) * 130 + 2 * l] = ax[8 + s];
      *(float2*)&red[((size_t)(12 + s) * 8 + wv) * 130 + 2 * l] = ah[8 + s];
    }
    __syncthreads();  // block-wide join
    float rp = 0, zp = 0, xnp = 0, hnp = 0;
#pragma unroll
    for (int w8 = 0; w8 < 8; ++w8) {
      rp  += red[((size_t)(0 + qg) * 8 + w8) * 130 + rr];
      zp  += red[((size_t)(4 + qg) * 8 + w8) * 130 + rr];
      xnp += red[((size_t)(8 + qg) * 8 + w8) * 130 + rr];
      hnp += red[((size_t)(12 + qg) * 8 + w8) * 130 + rr];
    }
    const float r = sigmoidf_(rp + bihs[0 + qg] + bhhs[0 + qg]);
    const float z = sigmoidf_(zp + bihs[4 + qg] + bhhs[4 + qg]);
    const float n = tanhf(xnp + bihs[8 + qg] + r * (hnp + bhhs[8 + qg]));
    const float hnew = (1.0f - z) * n + z * hprev;
    cohst1(big + (size_t)t * SLICE + og, hnew);
    asm volatile("s_waitcnt vmcnt(0)" ::: "memory");
    __syncthreads();
    if (tid == 0) fpost(gf, ng, (unsigned)(t + 1));
    if (t + 1 < NL) {
#pragma unroll
      for (int s = 0; s < 12; ++s) ax[s] = make_float2(0.0f, 0.0f);
      gdot12<true>(big + (size_t)(t + 2) * SLICE + boff, wxT, kp0, ax);
    }
    asm volatile("" ::: "memory");
  }
}

// ---- attn1 / attn2 (fp32, prior dispatches -> boundary invalidate ok) ----
__global__ __launch_bounds__(256) void attn1_kernel(float* __restrict__ ws) {
  const int l = blockIdx.x, tid = threadIdx.x;
  const float* const sl = ws + BIG_OFF + (size_t)l * SLICE + tid;
  const float* const vtt = ws + VT_OFF + tid;
  float acc = 0.0f;
#pragma unroll 8
  for (int k = 0; k < 512; ++k)
    acc += sl[(size_t)k * 256] * vtt[(size_t)k * 256];
  ws[LG_OFF + (size_t)l * 256 + tid] = acc;
}

__global__ __launch_bounds__(256) void attn2_kernel(float* __restrict__ ws) {
  __shared__ float red[8];
  const int b = blockIdx.x, tid = threadIdx.x;
  const float v = (tid < NL) ? ws[LG_OFF + (size_t)tid * 256 + b] : -3.0e38f;
  float m = v;
  for (int off = 32; off > 0; off >>= 1) m = fmaxf(m, __shfl_xor(m, off));
  if ((tid & 63) == 0) red[tid >> 6] = m;
  __syncthreads();
  m = fmaxf(fmaxf(red[0], red[1]), fmaxf(red[2], red[3]));
  const float e = (tid < NL) ? expf(v - m) : 0.0f;
  float s = e;
  for (int off = 32; off > 0; off >>= 1) s += __shfl_xor(s, off);
  __syncthreads();
  if ((tid & 63) == 0) red[4 + (tid >> 6)] = s;
  __syncthreads();
  s = red[4] + red[5] + red[6] + red[7];
  if (tid < NL) ws[ATT_OFF + (size_t)tid * 256 + b] = e / s;
}

// AUGRU dot (fp16). Activations at k-pair kp0+.. in [0,256); weight row
// offset WOFF (256 for x-part, 0 for h-part). DEPTH = loads in flight.
template <bool COH, int NQ, int SOFF, int WOFF, int DEPTH>
__device__ __forceinline__ void adot(const float* ap, const unsigned* wT24,
                                     int kp0, float* acc) {
  for (int g = 0; g < 32 / DEPTH; ++g) {
    const int kb = kp0 + g * DEPTH;
    float va[DEPTH], vb[DEPTH];
#pragma unroll
    for (int j = 0; j < DEPTH; ++j) {
      const float* p0 = ap + (size_t)(2 * (kb + j)) * 256;
      if (COH) { va[j] = cohld1(p0); vb[j] = cohld1(p0 + 256); }
      else     { va[j] = p0[0]; vb[j] = p0[256]; }
    }
#pragma unroll
    for (int j = 0; j < DEPTH; ++j) {
      const h2 r = pkh(va[j], vb[j]);
      const uint4* wq = (const uint4*)(wT24 + (size_t)(WOFF + kb + j) * 24) + SOFF;
#pragma unroll
      for (int q = 0; q < NQ; ++q) {
        const uint4 qq = wq[q];
        acc[4 * q + 0] = fd2(qq.x, r, acc[4 * q + 0]);
        acc[4 * q + 1] = fd2(qq.y, r, acc[4 * q + 1]);
        acc[4 * q + 2] = fd2(qq.z, r, acc[4 * q + 2]);
        acc[4 * q + 3] = fd2(qq.w, r, acc[4 * q + 3]);
      }
    }
  }
}

// ---- persistent AUGRU: fp16 dots; per-wave producer waits (8 flags/wave) ----
__global__ __launch_bounds__(512) void augru_kernel(const float* __restrict__ rw,
                                                    const float* __restrict__ rbias,
                                                    const float* __restrict__ uw,
                                                    const float* __restrict__ ubias,
                                                    const float* __restrict__ hw,
                                                    const float* __restrict__ hbias,
                                                    float* __restrict__ ws,
                                                    float* __restrict__ out) {
  __shared__ unsigned wT[512 * 24];   // [kp][24] half2-pairs: slot m*8+c
  __shared__ float red[24 * 8 * 66];
  __shared__ float rbs[8], ubs[8], hbs[8];

  const int rg = blockIdx.x >> 6;
  const int cg = blockIdx.x & 63;
  const int r0 = rg << 6, c0 = cg << 3;
  const int tid = threadIdx.x;

  for (int i = tid; i < 512 * 24; i += 512) {
    const int kp = i / 24, s = i % 24;
    const int m = s >> 3, c = s & 7;
    const float* const wm = (m == 0) ? rw : (m == 1) ? uw : hw;
    wT[i] = pk2(wm[(size_t)(c0 + c) * 1024 + 2 * kp],
                wm[(size_t)(c0 + c) * 1024 + 2 * kp + 1]);
  }
  if (tid < 8) {
    rbs[tid] = rbias[c0 + tid];
    ubs[tid] = ubias[c0 + tid];
    hbs[tid] = hbias[c0 + tid];
  }
  __syncthreads();

  float* const big = ws + BIG_OFF;
  float* const hrg = ws + HR_OFF;
  const float* const att = ws + ATT_OFF;
  unsigned* const fbase = (unsigned*)(ws + FLAGS_OFF);
  unsigned* const af1 = fbase + (size_t)(256 + (rg << 6)) * FSTRIDE;
  unsigned* const af2 = fbase + (size_t)(512 + (rg << 6)) * FSTRIDE;

  const int wv = tid >> 6, l = tid & 63;
  const int kp0 = wv << 5;
  const int boff = r0 + l;
  const int cq = tid >> 6;
  const int rr = tid & 63;
  const size_t og = (size_t)(c0 + cq) * 256 + r0 + rr;

  // prologue: x-dot t=0 (sseqT[0]; sc1 loads keep big slices L2-virgin)
  float ax[24];
#pragma unroll
  for (int s = 0; s < 24; ++s) ax[s] = 0.0f;
  adot<true, 6, 0, 256, 8>(big + boff, wT, kp0, ax);

  for (int t = 0; t < NL; ++t) {
    // per-wave wait on this wave's 8 producers (af2)
    if (t > 0) wwait(af2, wv << 3, (unsigned)t, 7);
    // h source: t=0 -> slice 199 (GRU final); t=1 -> slice 200; else t-1.
    const float* const hsrc =
        big + ((t == 0) ? 199ul : (t == 1) ? 200ul : (size_t)(t - 1)) * SLICE;
    const float hcur = hsrc[og];  // own cols: self-produced
    float ah[16];
#pragma unroll
    for (int s = 0; s < 16; ++s) ah[s] = 0.0f;
    adot<false, 4, 0, 0, 8>(hsrc + boff, wT, kp0, ah);
#pragma unroll
    for (int c = 0; c < 8; ++c) {
      red[((size_t)(0 + c) * 8 + wv) * 66 + l] = ax[c] + ah[c];
      red[((size_t)(8 + c) * 8 + wv) * 66 + l] = ax[8 + c] + ah[8 + c];
      red[((size_t)(16 + c) * 8 + wv) * 66 + l] = ax[16 + c];
    }
    __syncthreads();  // block-wide join
    float rp = 0, up = 0, xhp = 0;
#pragma unroll
    for (int w8 = 0; w8 < 8; ++w8) {
      rp  += red[((size_t)(0 + cq) * 8 + w8) * 66 + rr];
      up  += red[((size_t)(8 + cq) * 8 + w8) * 66 + rr];
      xhp += red[((size_t)(16 + cq) * 8 + w8) * 66 + rr];
    }
    const float rgate = sigmoidf_(rp + rbs[cq]);
    const float ug = sigmoidf_(up + ubs[cq]);
    cohst1(hrg + og, rgate * hcur);
    asm volatile("s_waitcnt vmcnt(0)" ::: "memory");
    __syncthreads();
    if (tid == 0) fpost(af1, cg, (unsigned)(t + 1));
    // pipelined x-dot for t+1 inside the af1 window (sc1 loads)
    if (t + 1 < NL) {
#pragma unroll
      for (int s = 0; s < 24; ++s) ax[s] = 0.0f;
      adot<true, 6, 0, 256, 8>(big + (size_t)(t + 1) * SLICE + boff, wT, kp0, ax);
    }
    asm volatile("" ::: "memory");
    // per-wave wait on this wave's 8 producers (af1)
    wwait(af1, wv << 3, (unsigned)(t + 1), 7);
    // phase2: hhat (hr via sc1, 16-deep batches)
    float ahh[8];
#pragma unroll
    for (int s = 0; s < 8; ++s) ahh[s] = 0.0f;
    adot<true, 2, 4, 0, 16>(hrg + boff, wT, kp0, ahh);
#pragma unroll
    for (int c = 0; c < 8; ++c)
      red[((size_t)c * 8 + wv) * 66 + l] = ahh[c];
    __syncthreads();
    float hhp = 0;
#pragma unroll
    for (int w8 = 0; w8 < 8; ++w8)
      hhp += red[((size_t)cq * 8 + w8) * 66 + rr];
    const float hh = tanhf(hhp + xhp + hbs[cq]);
    const float av = att[(size_t)t * 256 + r0 + rr];
    const float u = av * ug;
    const float hn = (1.0f - u) * hcur + u * hh;
    if (t == NL - 1) {
      out[(size_t)(r0 + rr) * 512 + c0 + cq] = hn;
    } else {
      float* const hdst = big + ((t == 0) ? 200ul : (size_t)t) * SLICE;
      cohst1(hdst + og, hn);
    }
    asm volatile("s_waitcnt vmcnt(0)" ::: "memory");
    __syncthreads();
    if (tid == 0) fpost(af2, cg, (unsigned)(t + 1));
  }
}

extern "C" void kernel_launch(void* const* d_in, const int* in_sizes, int n_in,
                              void* d_out, int out_size, void* d_ws, size_t ws_size,
                              hipStream_t stream) {
  (void)in_sizes; (void)n_in; (void)out_size; (void)ws_size;
  const float* session = (const float*)d_in[0];
  const float* target  = (const float*)d_in[1];
  const float* w       = (const float*)d_in[2];
  const float* wih     = (const float*)d_in[3];
  const float* whh     = (const float*)d_in[4];
  const float* bih     = (const float*)d_in[5];
  const float* bhh     = (const float*)d_in[6];
  const float* rw      = (const float*)d_in[7];
  const float* rb      = (const float*)d_in[8];
  const float* uw      = (const float*)d_in[9];
  const float* ub      = (const float*)d_in[10];
  const float* hw      = (const float*)d_in[11];
  const float* hb      = (const float*)d_in[12];
  float* ws  = (float*)d_ws;
  float* out = (float*)d_out;

  hipLaunchKernelGGL(init_kernel, dim3(4), dim3(256), 0, stream, ws);
  hipLaunchKernelGGL(transpose_kernel, dim3(1600, 4), dim3(256), 0, stream, session, ws);
  hipLaunchKernelGGL(vt_kernel, dim3(256), dim3(256), 0, stream, w, target, ws);
  hipLaunchKernelGGL(gru_kernel, dim3(256), dim3(512), 0, stream,
                     wih, whh, bih, bhh, ws);
  hipLaunchKernelGGL(attn1_kernel, dim3(200), dim3(256), 0, stream, ws);
  hipLaunchKernelGGL(attn2_kernel, dim3(256), dim3(256), 0, stream, ws);
  hipLaunchKernelGGL(augru_kernel, dim3(256), dim3(512), 0, stream,
                     rw, rb, uw, ub, hw, hb, ws, out);
}